// Round 3
// baseline (2142.390 us; speedup 1.0000x reference)
//
#include <hip/hip_runtime.h>

#define Bdim 16
#define Cdim 512
#define Hdim 128
#define Wdim 128
#define NS 8
// per channel: H*W = 16384 floats; per thread: 64 floats = 16 float4

typedef float fvec4 __attribute__((ext_vector_type(4)));

// workspace layout: [rc: B*H ints][done: B ints][F: B*C floats]
#define RC_OFF   0
#define DONE_OFF (Bdim * Hdim)
#define ZERO_BYTES ((Bdim * Hdim + Bdim) * sizeof(int))

__global__ __launch_bounds__(256) void chan_reduce_fused(const float* __restrict__ x,
                                                         int* __restrict__ ws_i,
                                                         float* __restrict__ F,
                                                         float* __restrict__ out) {
    int* __restrict__ rc   = ws_i + RC_OFF;
    int* __restrict__ done = ws_i + DONE_OFF;

    const int bid = blockIdx.x;          // b*C + c
    const int tid = threadIdx.x;
    const int b = bid >> 9;              // bid / Cdim
    const fvec4* __restrict__ p = (const fvec4*)(x + ((size_t)bid << 14));

    fvec4 r[16];
    float tmax0 = -INFINITY, tmax1 = -INFINITY;
    float tsum0 = 0.f, tsum1 = 0.f;
#pragma unroll
    for (int i = 0; i < 16; i += 2) {
        r[i]     = __builtin_nontemporal_load(&p[i * 256 + tid]);
        r[i + 1] = __builtin_nontemporal_load(&p[(i + 1) * 256 + tid]);
        tsum0 += (r[i].x + r[i].y) + (r[i].z + r[i].w);
        tsum1 += (r[i+1].x + r[i+1].y) + (r[i+1].z + r[i+1].w);
        tmax0 = fmaxf(tmax0, fmaxf(fmaxf(r[i].x, r[i].y), fmaxf(r[i].z, r[i].w)));
        tmax1 = fmaxf(tmax1, fmaxf(fmaxf(r[i+1].x, r[i+1].y), fmaxf(r[i+1].z, r[i+1].w)));
    }
    float tsum = tsum0 + tsum1;
    float tmax = fmaxf(tmax0, tmax1);

    // wave (64-lane) reduction
#pragma unroll
    for (int off = 32; off > 0; off >>= 1) {
        tsum += __shfl_down(tsum, off, 64);
        tmax = fmaxf(tmax, __shfl_down(tmax, off, 64));
    }

    __shared__ float smax[4], ssum[4];
    const int wave = tid >> 6;
    if ((tid & 63) == 0) { smax[wave] = tmax; ssum[wave] = tsum; }
    __syncthreads();

    const float bmax = fmaxf(fmaxf(smax[0], smax[1]), fmaxf(smax[2], smax[3]));
    if (tid == 0) {
        F[bid] = (ssum[0] + ssum[1] + ssum[2] + ssum[3]) * (1.0f / Wdim);
    }

    // count elements equal to channel max, per row.
    // thread's float4 #i lives in row i*8 + (tid>>5)
    const int rsub = tid >> 5;
#pragma unroll
    for (int i = 0; i < 16; ++i) {
        int cnt = (r[i].x == bmax) + (r[i].y == bmax) +
                  (r[i].z == bmax) + (r[i].w == bmax);
        if (cnt) atomicAdd(&rc[b * Hdim + i * 8 + rsub], cnt);
    }

    // ---- last-block-per-batch epilogue ----
    __threadfence();   // release rc writes (device scope)
    __shared__ int s_last;
    if (tid == 0) {
        int prev = atomicAdd(&done[b], 1);
        s_last = (prev == Cdim - 1);
    }
    __syncthreads();
    if (!s_last) return;
    __threadfence();   // acquire

    __shared__ int s_Hc[Hdim + 1];
    __shared__ float s_sub[NS];

    if (tid < Hdim) s_Hc[tid + 1] = atomicAdd(&rc[b * Hdim + tid], 0);  // device-scope read
    __syncthreads();

    if (tid == 0) {
        int acc = 0;
        s_Hc[0] = 0;
        for (int i = 1; i <= Hdim; ++i) { acc += s_Hc[i]; s_Hc[i] = acc; }
        // s_Hc is now inclusive cumsum; exclusive Hc[j] == s_Hc[j] with s_Hc[0]=0
        float hks[NS + 1];
        for (int k = 0; k <= NS; ++k) hks[k] = 0.f;
        hks[NS] = (float)Hdim;
        int k = 1;
        for (int j = 1; j <= Hdim - 2; ++j) {
            int t = (k * Cdim) / NS;
            if (k < NS && s_Hc[j] <= t && s_Hc[j + 1] > t) {
                hks[k] = (float)j;
                ++k;
            }
        }
        for (int q = 0; q < NS; ++q) s_sub[q] = hks[q + 1] - hks[q];
    }
    __syncthreads();

    // out[b, k*C + c] = F[b, c] / hk_sub[b, k]
    const float* Fb = F + b * Cdim;
    for (int idx = tid; idx < NS * Cdim; idx += 256) {
        int k = idx >> 9;          // idx / Cdim
        int c = idx & (Cdim - 1);
        out[b * (NS * Cdim) + idx] = Fb[c] / s_sub[k];
    }
}

extern "C" void kernel_launch(void* const* d_in, const int* in_sizes, int n_in,
                              void* d_out, int out_size, void* d_ws, size_t ws_size,
                              hipStream_t stream) {
    const float* x = (const float*)d_in[0];
    float* out = (float*)d_out;
    int* ws_i = (int*)d_ws;
    float* F = (float*)((char*)d_ws + ZERO_BYTES);

    (void)hipMemsetAsync(d_ws, 0, ZERO_BYTES, stream);
    chan_reduce_fused<<<Bdim * Cdim, 256, 0, stream>>>(x, ws_i, F, out);
}